// Round 4
// baseline (474.105 us; speedup 1.0000x reference)
//
#include <hip/hip_runtime.h>
#include <hip/hip_bf16.h>

// CP-decomposition eval: out[c][n] = lerp0[c](x) * lerp1[c](y) * lerp2[c](z)
//
// v2: transposed-LDS + quad-gather design.
//   - Tables staged in LDS TRANSPOSED: lds[axis][g][cLocal] (row = 16 comps,
//     64 B, 16 B-aligned) so one ds_read_b128 fetches 4 comps of row g.
//   - Wave = 16 points x 4 comp-quads (lane = q*16 + p). Per point-iter a
//     lane does 6 ds_read_b128 (3 axes x rows {i,i+1}) instead of 96
//     scalar ds_read_b32 of the v1 design -> DS pipe ~250us -> ~55us.
//   - C split into 3 groups of 16 (57.6 KB LDS -> 2 blocks/CU, 16 waves/CU).
//   - Stores: 4 coalesced nontemporal dword streams (16-consecutive-point
//     runs per 16-lane group), overlapping DS gathers on the VMEM pipe.

#define NCOMP   48
#define CSUB    16
#define NGROUP  (NCOMP / CSUB)
#define GSZ     300
#define BLOCK   512            // 8 waves
#define PTS_PER_BLOCK (8 * 16) // 8 waves x 16 points
#define GRID_X  512

__global__ __launch_bounds__(BLOCK, 4)
void cp_kernel(const float* __restrict__ xyz,
               const float* __restrict__ p0,
               const float* __restrict__ p1,
               const float* __restrict__ p2,
               float* __restrict__ out,
               int N)
{
    // [axis][g][cLocal], row stride 16 floats = 64 B (16B-aligned quads)
    __shared__ __align__(16) float lds[3][GSZ][CSUB];

    const int cg = blockIdx.y;

    // ---- stage tables transposed (global [c][g] -> LDS [g][c]) ----
    {
        const float* srcs[3] = { p0 + cg * (CSUB * GSZ),
                                 p1 + cg * (CSUB * GSZ),
                                 p2 + cg * (CSUB * GSZ) };
        #pragma unroll
        for (int ax = 0; ax < 3; ++ax) {
            const float* s = srcs[ax];
            for (int i = threadIdx.x; i < CSUB * GSZ; i += BLOCK) {
                const int c = i / GSZ;          // magic-div by const
                const int g = i - c * GSZ;
                lds[ax][g][c] = s[i];
            }
        }
    }
    __syncthreads();

    const int lane = threadIdx.x & 63;
    const int wv   = threadIdx.x >> 6;   // 0..7
    const int p    = lane & 15;          // point sub-index within wave
    const int q    = lane >> 4;          // comp-quad 0..3

    const int    stride = GRID_X * PTS_PER_BLOCK;
    const size_t cbase  = (size_t)(cg * CSUB + 4 * q) * (size_t)N;

    for (int n = blockIdx.x * PTS_PER_BLOCK + wv * 16 + p; n < N; n += stride) {
        const float x = xyz[3 * n + 0];
        const float y = xyz[3 * n + 1];
        const float z = xyz[3 * n + 2];

        const float pos0 = (x + 1.0f) * 0.5f * (float)(GSZ - 1);
        const float pos1 = (y + 1.0f) * 0.5f * (float)(GSZ - 1);
        const float pos2 = (z + 1.0f) * 0.5f * (float)(GSZ - 1);

        // ic = min(floor(pos), G-2); w = pos - ic  (w==1 at top edge) —
        // exactly reproduces ref's i0/i1/w including the i1 clamp.
        const int ic0 = min((int)pos0, GSZ - 2);
        const int ic1 = min((int)pos1, GSZ - 2);
        const int ic2 = min((int)pos2, GSZ - 2);
        const float w0 = pos0 - (float)ic0, om0 = 1.0f - w0;
        const float w1 = pos1 - (float)ic1, om1 = 1.0f - w1;
        const float w2 = pos2 - (float)ic2, om2 = 1.0f - w2;

        const float4 a0 = *(const float4*)&lds[0][ic0    ][4 * q];
        const float4 a1 = *(const float4*)&lds[0][ic0 + 1][4 * q];
        const float4 b0 = *(const float4*)&lds[1][ic1    ][4 * q];
        const float4 b1 = *(const float4*)&lds[1][ic1 + 1][4 * q];
        const float4 c0 = *(const float4*)&lds[2][ic2    ][4 * q];
        const float4 c1 = *(const float4*)&lds[2][ic2 + 1][4 * q];

        // same eval order as reference: p0*(1-w) + p1*w
        const float Ax = a0.x * om0 + a1.x * w0;
        const float Ay = a0.y * om0 + a1.y * w0;
        const float Az = a0.z * om0 + a1.z * w0;
        const float Aw = a0.w * om0 + a1.w * w0;
        const float Bx = b0.x * om1 + b1.x * w1;
        const float By = b0.y * om1 + b1.y * w1;
        const float Bz = b0.z * om1 + b1.z * w1;
        const float Bw = b0.w * om1 + b1.w * w1;
        const float Cx = c0.x * om2 + c1.x * w2;
        const float Cy = c0.y * om2 + c1.y * w2;
        const float Cz = c0.z * om2 + c1.z * w2;
        const float Cw = c0.w * om2 + c1.w * w2;

        float* o = out + cbase + n;
        __builtin_nontemporal_store(Ax * Bx * Cx, o); o += N;
        __builtin_nontemporal_store(Ay * By * Cy, o); o += N;
        __builtin_nontemporal_store(Az * Bz * Cz, o); o += N;
        __builtin_nontemporal_store(Aw * Bw * Cw, o);
    }
}

extern "C" void kernel_launch(void* const* d_in, const int* in_sizes, int n_in,
                              void* d_out, int out_size, void* d_ws, size_t ws_size,
                              hipStream_t stream)
{
    const float* xyz = (const float*)d_in[0];
    const float* p0  = (const float*)d_in[1];
    const float* p1  = (const float*)d_in[2];
    const float* p2  = (const float*)d_in[3];
    float* out = (float*)d_out;
    const int N = in_sizes[0] / 3;

    dim3 grid(GRID_X, NGROUP, 1);
    dim3 block(BLOCK, 1, 1);
    cp_kernel<<<grid, block, 0, stream>>>(xyz, p0, p1, p2, out, N);
}

// Round 5
// 461.254 us; speedup vs baseline: 1.0279x; 1.0279x over previous
//
#include <hip/hip_runtime.h>
#include <hip/hip_bf16.h>

// CP-decomposition eval: out[c][n] = lerp0[c](x) * lerp1[c](y) * lerp2[c](z)
//
// v3: attack the store-path / latency-chain, not DS (v1->v2 falsified DS-bound).
//   - NO nontemporal stores: match the known-good 6.3 TB/s write path (L2).
//   - CSUB=8 -> LDS 28.8 KB/block -> 5 blocks/CU (20 waves/CU vs 16 before).
//   - xyz software prefetch issued BEFORE the stores: the next iteration's
//     s_waitcnt for the loads (vmcnt is in-order) no longer drains stores.
//   - Lane = h*32 + p: 32 points x 2 comp-quads per wave; 6 ds_read_b128
//     per wave-iter for 256 outputs (same DS/output ratio as v2).

#define NCOMP   48
#define CSUB    8
#define NGROUP  (NCOMP / CSUB)      // 6
#define GSZ     300
#define BLOCK   256                  // 4 waves
#define PTSW    32                   // points per wave-iter
#define PTS_PER_BLOCK (4 * PTSW)     // 128
#define GRID_X  512

__global__ __launch_bounds__(BLOCK, 6)
void cp_kernel(const float* __restrict__ xyz,
               const float* __restrict__ p0,
               const float* __restrict__ p1,
               const float* __restrict__ p2,
               float* __restrict__ out,
               int N)
{
    // [axis][g][cLocal], row = 8 floats = 32 B (16B-aligned quads)
    __shared__ __align__(16) float lds[3][GSZ][CSUB];

    const int cg = blockIdx.y;

    // ---- stage tables transposed (global [c][g] -> LDS [g][c]) ----
    {
        const float* srcs[3] = { p0 + cg * (CSUB * GSZ),
                                 p1 + cg * (CSUB * GSZ),
                                 p2 + cg * (CSUB * GSZ) };
        #pragma unroll
        for (int ax = 0; ax < 3; ++ax) {
            const float* s = srcs[ax];
            for (int i = threadIdx.x; i < CSUB * GSZ; i += BLOCK) {
                const int c = i / GSZ;          // const-div -> magic mul
                const int g = i - c * GSZ;
                lds[ax][g][c] = s[i];
            }
        }
    }
    __syncthreads();

    const int lane = threadIdx.x & 63;
    const int wv   = threadIdx.x >> 6;   // 0..3
    const int p    = lane & 31;          // point sub-index within wave
    const int h    = lane >> 5;          // comp-quad 0..1

    const int    stride = GRID_X * PTS_PER_BLOCK;
    const size_t cbase  = (size_t)(cg * CSUB + 4 * h) * (size_t)N;

    int n = blockIdx.x * PTS_PER_BLOCK + wv * PTSW + p;   // < 65536 <= N
    float x = xyz[3 * n + 0];
    float y = xyz[3 * n + 1];
    float z = xyz[3 * n + 2];

    for (; n < N; n += stride) {
        // -------- prefetch next iteration's xyz (issued before stores) -----
        const int nn = min(n + stride, N - 1);
        const float xx = xyz[3 * nn + 0];
        const float yy = xyz[3 * nn + 1];
        const float zz = xyz[3 * nn + 2];

        // -------- interpolation setup --------
        const float pos0 = (x + 1.0f) * 0.5f * (float)(GSZ - 1);
        const float pos1 = (y + 1.0f) * 0.5f * (float)(GSZ - 1);
        const float pos2 = (z + 1.0f) * 0.5f * (float)(GSZ - 1);

        // ic = min(floor(pos), G-2); w = pos - ic (w==1 at top edge)
        // reproduces ref's i0/i1/w incl. the i1 = min(i0+1, G-1) clamp.
        const int ic0 = min((int)pos0, GSZ - 2);
        const int ic1 = min((int)pos1, GSZ - 2);
        const int ic2 = min((int)pos2, GSZ - 2);
        const float w0 = pos0 - (float)ic0, om0 = 1.0f - w0;
        const float w1 = pos1 - (float)ic1, om1 = 1.0f - w1;
        const float w2 = pos2 - (float)ic2, om2 = 1.0f - w2;

        const float4 a0 = *(const float4*)&lds[0][ic0    ][4 * h];
        const float4 a1 = *(const float4*)&lds[0][ic0 + 1][4 * h];
        const float4 b0 = *(const float4*)&lds[1][ic1    ][4 * h];
        const float4 b1 = *(const float4*)&lds[1][ic1 + 1][4 * h];
        const float4 c0 = *(const float4*)&lds[2][ic2    ][4 * h];
        const float4 c1 = *(const float4*)&lds[2][ic2 + 1][4 * h];

        const float Ax = a0.x * om0 + a1.x * w0;
        const float Ay = a0.y * om0 + a1.y * w0;
        const float Az = a0.z * om0 + a1.z * w0;
        const float Aw = a0.w * om0 + a1.w * w0;
        const float Bx = b0.x * om1 + b1.x * w1;
        const float By = b0.y * om1 + b1.y * w1;
        const float Bz = b0.z * om1 + b1.z * w1;
        const float Bw = b0.w * om1 + b1.w * w1;
        const float Cx = c0.x * om2 + c1.x * w2;
        const float Cy = c0.y * om2 + c1.y * w2;
        const float Cz = c0.z * om2 + c1.z * w2;
        const float Cw = c0.w * om2 + c1.w * w2;

        float* o = out + cbase + n;
        o[0]             = Ax * Bx * Cx;
        o[(size_t)N]     = Ay * By * Cy;
        o[(size_t)2 * N] = Az * Bz * Cz;
        o[(size_t)3 * N] = Aw * Bw * Cw;

        x = xx; y = yy; z = zz;
    }
}

extern "C" void kernel_launch(void* const* d_in, const int* in_sizes, int n_in,
                              void* d_out, int out_size, void* d_ws, size_t ws_size,
                              hipStream_t stream)
{
    const float* xyz = (const float*)d_in[0];
    const float* p0  = (const float*)d_in[1];
    const float* p1  = (const float*)d_in[2];
    const float* p2  = (const float*)d_in[3];
    float* out = (float*)d_out;
    const int N = in_sizes[0] / 3;

    dim3 grid(GRID_X, NGROUP, 1);
    dim3 block(BLOCK, 1, 1);
    cp_kernel<<<grid, block, 0, stream>>>(xyz, p0, p1, p2, out, N);
}